// Round 1
// baseline (185.380 us; speedup 1.0000x reference)
//
#include <hip/hip_runtime.h>
#include <math.h>

// MaxPool3d: in (2,32,128,128,128) f32, k=3 s=2 p=1 (-inf pad) -> out (2,32,64,64,64) f32
// Wave = one output W-row (64 lanes). Per (d,h) tap-row: one aligned float2 load
// (covers taps 2w, 2w+1) + one shfl_up for tap 2w-1. 9 tap-rows per output.

#define D_IN 128
#define H_IN 128
#define W_IN 128
#define D_OUT 64
#define H_OUT 64
#define NC 64  // 2*32

__global__ __launch_bounds__(256) void maxpool3d_k3s2p1(const float* __restrict__ x,
                                                        float* __restrict__ out) {
    const int tx = threadIdx.x & 63;   // w_out (lane)
    const int ty = threadIdx.x >> 6;   // h-row within block tile
    const int h_out = blockIdx.x * 4 + ty;
    const int d_out = blockIdx.y;
    const int nc    = blockIdx.z;

    const int w0    = tx * 2;          // even -> aligned float2
    const int d_in0 = 2 * d_out - 1;
    const int h_in0 = 2 * h_out - 1;

    const float* __restrict__ base = x + (size_t)nc * (D_IN * H_IN * W_IN);

    float m = -INFINITY;
#pragma unroll
    for (int kd = 0; kd < 3; ++kd) {
        const int d = d_in0 + kd;
        if (d < 0) continue;           // only kd=0 at d_out=0 can be out of range
#pragma unroll
        for (int kh = 0; kh < 3; ++kh) {
            const int h = h_in0 + kh;
            if (h < 0) continue;       // only kh=0 at h_out=0
            const float2 v =
                *reinterpret_cast<const float2*>(base + ((size_t)d * H_IN + h) * W_IN + w0);
            float left = __shfl_up(v.y, 1, 64);   // previous lane's x[2w-1]
            if (tx == 0) left = -INFINITY;        // -inf pad at w=-1
            m = fmaxf(m, fmaxf(left, fmaxf(v.x, v.y)));
        }
    }

    out[(((size_t)nc * D_OUT + d_out) * H_OUT + h_out) * 64 + tx] = m;
}

extern "C" void kernel_launch(void* const* d_in, const int* in_sizes, int n_in,
                              void* d_out, int out_size, void* d_ws, size_t ws_size,
                              hipStream_t stream) {
    const float* x = (const float*)d_in[0];
    float* out = (float*)d_out;
    dim3 grid(H_OUT / 4, D_OUT, NC);   // 16 x 64 x 64 blocks
    dim3 block(256);
    maxpool3d_k3s2p1<<<grid, block, 0, stream>>>(x, out);
}

// Round 2
// 149.592 us; speedup vs baseline: 1.2392x; 1.2392x over previous
//
#include <hip/hip_runtime.h>
#include <math.h>

// MaxPool3d: in (2,32,128,128,128) f32, k=3 s=2 p=1 (-inf pad) -> out (2,32,64,64,64) f32
// Block = (h-tile of 4 rows) x (d-half). Slides over d_in planes so every input
// plane is fetched once per block: per plane compute the (h,w)-pooled value in
// registers, fold into a 1-float d-window accumulator. Wave = one output W-row;
// per tap-row one aligned float2 load (taps 2w,2w+1) + shfl_up for 2w-1.

#define D_IN 128
#define H_IN 128
#define W_IN 128
#define D_OUT 64
#define H_OUT 64
#define NC 64  // 2*32

__global__ __launch_bounds__(256) void maxpool3d_k3s2p1_slide(const float* __restrict__ x,
                                                              float* __restrict__ out) {
    const int tx = threadIdx.x & 63;   // w_out (lane)
    const int ty = threadIdx.x >> 6;   // h-row within block tile
    const int h_out = blockIdx.x * 4 + ty;
    const int k0    = blockIdx.y * 32; // first d_out of this half
    const int nc    = blockIdx.z;

    const int w0    = tx * 2;          // even -> aligned float2
    const int h_in0 = 2 * h_out - 1;

    const float* __restrict__ base = x + (size_t)nc * (D_IN * H_IN * W_IN);
    float* __restrict__ obase = out + (size_t)nc * (D_OUT * H_OUT * 64) + h_out * 64 + tx;

    // (h,w)-pooled max of plane d for this thread's output row/col
    auto planeMax = [&](int d) -> float {
        float m = -INFINITY;
#pragma unroll
        for (int kh = 0; kh < 3; ++kh) {
            const int h = h_in0 + kh;
            if (h < 0) continue;       // wave-uniform (only h_out==0, kh==0)
            const float2 v =
                *reinterpret_cast<const float2*>(base + ((size_t)d * H_IN + h) * W_IN + w0);
            float left = __shfl_up(v.y, 1, 64);   // previous lane's x[2w-1]
            if (tx == 0) left = -INFINITY;        // -inf pad at w=-1
            m = fmaxf(m, fmaxf(left, fmaxf(v.x, v.y)));
        }
        return m;
    };

    // init acc = max over d_in {2k0-1, 2k0}
    float acc;
    if (k0 == 0) {
        acc = planeMax(0);             // d_in=-1 is -inf pad
    } else {
        acc = fmaxf(planeMax(2 * k0 - 1), planeMax(2 * k0));
    }

#pragma unroll 2
    for (int i = 0; i < 31; ++i) {
        const int k = k0 + i;
        const float v1 = planeMax(2 * k + 1);               // finishes window k
        obase[(size_t)k * (H_OUT * 64)] = fmaxf(acc, v1);
        const float v2 = planeMax(2 * k + 2);               // starts window k+1
        acc = fmaxf(v1, v2);
    }
    // last k of this half: window {2k-1, 2k, 2k+1}, 2k+1 <= 127
    const int kl = k0 + 31;
    const float v1 = planeMax(2 * kl + 1);
    obase[(size_t)kl * (H_OUT * 64)] = fmaxf(acc, v1);
}

extern "C" void kernel_launch(void* const* d_in, const int* in_sizes, int n_in,
                              void* d_out, int out_size, void* d_ws, size_t ws_size,
                              hipStream_t stream) {
    const float* x = (const float*)d_in[0];
    float* out = (float*)d_out;
    dim3 grid(H_OUT / 4, 2, NC);       // 16 x 2 x 64 = 2048 blocks
    dim3 block(256);
    maxpool3d_k3s2p1_slide<<<grid, block, 0, stream>>>(x, out);
}

// Round 3
// 124.276 us; speedup vs baseline: 1.4917x; 1.2037x over previous
//
#include <hip/hip_runtime.h>
#include <math.h>

// MaxPool3d: in (2,32,128,128,128) f32, k=3 s=2 p=1 (-inf pad) -> out (2,32,64,64,64) f32
// Thread = 2x2 (h_out x w_out) patch, sliding over d (d-quarter per block).
// Per plane: 5 float4 row-loads (w taps 4t..4t+3; left tap 4t-1 via shfl_up),
// w-pool each row once, share middle row between the two h-windows, fold into
// 4-float d-window accumulator. Every input plane fetched once per block.

#define D_IN 128
#define H_IN 128
#define W_IN 128
#define D_OUT 64
#define H_OUT 64
#define W_OUT 64
#define NC 64  // 2*32

__device__ __forceinline__ float4 fmax4(float4 a, float4 b) {
    return make_float4(fmaxf(a.x, b.x), fmaxf(a.y, b.y), fmaxf(a.z, b.z), fmaxf(a.w, b.w));
}

__global__ __launch_bounds__(256) void maxpool3d_k3s2p1_v3(const float* __restrict__ x,
                                                           float* __restrict__ out) {
    const int t  = threadIdx.x & 31;   // w-pair index: w_out = 2t, 2t+1
    const int hy = threadIdx.x >> 5;   // h-pair index within block (0..7)
    const int h_out0 = blockIdx.x * 16 + hy * 2;   // first of 2 h_out rows
    const int k0     = blockIdx.y * 16;            // first d_out of this quarter
    const int nc     = blockIdx.z;

    const int h_in0 = 2 * h_out0 - 1;              // first of 5 input rows (may be -1)
    const bool h0ok = (h_in0 >= 0);                // false only for h_out0 == 0

    const float* __restrict__ base =
        x + (size_t)nc * (D_IN * H_IN * W_IN) + (ptrdiff_t)h_in0 * W_IN + 4 * t;
    float* __restrict__ obase =
        out + ((size_t)nc * D_OUT) * (H_OUT * W_OUT) + (size_t)h_out0 * W_OUT + 2 * t;

    // (h,w)-pooled 2x2 patch of plane d: {h0w0, h0w1, h1w0, h1w1}
    auto planeMax = [&](int d) -> float4 {
        const float* p = base + (size_t)d * (H_IN * W_IN);
        float rwx[5], rwy[5];
#pragma unroll
        for (int r = 0; r < 5; ++r) {
            float4 v;
            if (r == 0 && !h0ok) {
                v = make_float4(-INFINITY, -INFINITY, -INFINITY, -INFINITY);
            } else {
                v = *reinterpret_cast<const float4*>(p + r * W_IN);
            }
            float left = __shfl_up(v.w, 1, 64);    // neighbor's x[4t-1]
            if (t == 0) left = -INFINITY;          // -inf pad at w=-1
            rwx[r] = fmaxf(left, fmaxf(v.x, v.y)); // w_out = 2t
            rwy[r] = fmaxf(v.y, fmaxf(v.z, v.w));  // w_out = 2t+1
        }
        float4 ph;
        ph.x = fmaxf(rwx[0], fmaxf(rwx[1], rwx[2]));
        ph.y = fmaxf(rwy[0], fmaxf(rwy[1], rwy[2]));
        ph.z = fmaxf(rwx[2], fmaxf(rwx[3], rwx[4]));
        ph.w = fmaxf(rwy[2], fmaxf(rwy[3], rwy[4]));
        return ph;
    };

    auto storeK = [&](int k, float4 o) {
        float* orow = obase + (size_t)k * (H_OUT * W_OUT);
        *reinterpret_cast<float2*>(orow) = make_float2(o.x, o.y);
        *reinterpret_cast<float2*>(orow + W_OUT) = make_float2(o.z, o.w);
    };

    // init acc = max over planes {2k0-1, 2k0}
    float4 acc;
    if (k0 == 0) {
        acc = planeMax(0);                         // plane -1 is -inf pad
    } else {
        acc = fmax4(planeMax(2 * k0 - 1), planeMax(2 * k0));
    }

#pragma unroll 2
    for (int i = 0; i < 15; ++i) {
        const int k = k0 + i;
        const float4 v1 = planeMax(2 * k + 1);     // finishes window k
        storeK(k, fmax4(acc, v1));
        const float4 v2 = planeMax(2 * k + 2);     // starts window k+1
        acc = fmax4(v1, v2);
    }
    const int kl = k0 + 15;                        // last window of quarter
    storeK(kl, fmax4(acc, planeMax(2 * kl + 1)));
}

extern "C" void kernel_launch(void* const* d_in, const int* in_sizes, int n_in,
                              void* d_out, int out_size, void* d_ws, size_t ws_size,
                              hipStream_t stream) {
    const float* x = (const float*)d_in[0];
    float* out = (float*)d_out;
    dim3 grid(H_OUT / 16, 4, NC);   // 4 x 4 x 64 = 1024 blocks
    dim3 block(256);
    maxpool3d_k3s2p1_v3<<<grid, block, 0, stream>>>(x, out);
}

// Round 5
// 118.233 us; speedup vs baseline: 1.5679x; 1.0511x over previous
//
#include <hip/hip_runtime.h>
#include <math.h>

// MaxPool3d: in (2,32,128,128,128) f32, k=3 s=2 p=1 (-inf pad) -> out (2,32,64,64,64) f32
// Thread = 2x2 (h_out x w_out) patch sliding over d (d-eighth per block).
// Explicit 2-plane software pipeline: loads for the next plane are issued before
// pooling the current one (named register buffers A/B, no runtime indexing).
// Per plane: 5 float4 row-loads; left tap 4t-1 via shfl_up; nontemporal stores.

#define D_IN 128
#define H_IN 128
#define W_IN 128
#define HW (H_IN * W_IN)
#define D_OUT 64
#define H_OUT 64
#define W_OUT 64
#define NC 64   // 2*32
#define KPB 8   // d_out windows per block

typedef float vf2 __attribute__((ext_vector_type(2)));  // native vec for nontemporal store

struct P5 { float4 r0, r1, r2, r3, r4; };

__device__ __forceinline__ float4 fmax4(float4 a, float4 b) {
    return make_float4(fmaxf(a.x, b.x), fmaxf(a.y, b.y), fmaxf(a.z, b.z), fmaxf(a.w, b.w));
}

__device__ __forceinline__ P5 loadPlane(const float* __restrict__ p, int r0off) {
    P5 v;
    v.r0 = *reinterpret_cast<const float4*>(p + r0off);   // row h_in0 (clamped to 0 if pad)
    v.r1 = *reinterpret_cast<const float4*>(p + W_IN);
    v.r2 = *reinterpret_cast<const float4*>(p + 2 * W_IN);
    v.r3 = *reinterpret_cast<const float4*>(p + 3 * W_IN);
    v.r4 = *reinterpret_cast<const float4*>(p + 4 * W_IN);
    return v;
}

__device__ __forceinline__ float rowL(float4 v, int t) {
    float left = __shfl_up(v.w, 1, 64);   // neighbor's x[4t-1]
    if (t == 0) left = -INFINITY;         // -inf pad at w=-1 (also kills cross-half garbage)
    return fmaxf(left, fmaxf(v.x, v.y));  // w_out = 2t
}
__device__ __forceinline__ float rowR(float4 v) {
    return fmaxf(v.y, fmaxf(v.z, v.w));   // w_out = 2t+1
}

__device__ __forceinline__ float4 poolPlane(const P5& v, int t, bool h0ok) {
    float ax0 = rowL(v.r0, t), ay0 = rowR(v.r0);
    if (!h0ok) { ax0 = -INFINITY; ay0 = -INFINITY; }   // row -1 is -inf pad
    float ax1 = rowL(v.r1, t), ay1 = rowR(v.r1);
    float ax2 = rowL(v.r2, t), ay2 = rowR(v.r2);
    float ax3 = rowL(v.r3, t), ay3 = rowR(v.r3);
    float ax4 = rowL(v.r4, t), ay4 = rowR(v.r4);
    float4 o;
    o.x = fmaxf(ax0, fmaxf(ax1, ax2));
    o.y = fmaxf(ay0, fmaxf(ay1, ay2));
    o.z = fmaxf(ax2, fmaxf(ax3, ax4));
    o.w = fmaxf(ay2, fmaxf(ay3, ay4));
    return o;
}

__global__ __launch_bounds__(256) void maxpool3d_k3s2p1_v4(const float* __restrict__ x,
                                                           float* __restrict__ out) {
    const int t  = threadIdx.x & 31;   // w-pair index: w_out = 2t, 2t+1
    const int hy = threadIdx.x >> 5;   // h-pair index within block (0..7)
    const int h_out0 = blockIdx.x * 16 + hy * 2;
    const int k0     = blockIdx.y * KPB;
    const int nc     = blockIdx.z;

    const int h_in0 = 2 * h_out0 - 1;
    const bool h0ok = (h_in0 >= 0);
    const int r0off = h0ok ? 0 : W_IN;   // clamp pad row's address to row 0 (value replaced)

    const float* __restrict__ base =
        x + (size_t)nc * (D_IN * HW) + (ptrdiff_t)h_in0 * W_IN + 4 * t;
    float* __restrict__ obase =
        out + (size_t)nc * (D_OUT * H_OUT * W_OUT) + (size_t)h_out0 * W_OUT + 2 * t;

    auto storeK = [&](int k, float4 o) {
        float* orow = obase + (size_t)k * (H_OUT * W_OUT);
        vf2 lo = {o.x, o.y}, hi = {o.z, o.w};
        __builtin_nontemporal_store(lo, reinterpret_cast<vf2*>(orow));
        __builtin_nontemporal_store(hi, reinterpret_cast<vf2*>(orow + W_OUT));
    };

    P5 A, B;
    float4 acc;
    // Establish invariant: acc = max over planes {2k0-1, 2k0}; A = plane 2k0+1 (issued).
    if (k0 == 0) {
        A = loadPlane(base, r0off);                           // plane 0 (plane -1 = pad)
        P5 A1 = loadPlane(base + HW, r0off);                  // plane 1, issued early
        acc = poolPlane(A, t, h0ok);
        A = A1;
    } else {
        A = loadPlane(base + (size_t)(2 * k0 - 1) * HW, r0off);
        B = loadPlane(base + (size_t)(2 * k0) * HW, r0off);
        float4 a0 = poolPlane(A, t, h0ok);
        A = loadPlane(base + (size_t)(2 * k0 + 1) * HW, r0off);
        acc = fmax4(a0, poolPlane(B, t, h0ok));
    }

#pragma unroll 1
    for (int k = k0; k < k0 + KPB - 1; ++k) {
        B = loadPlane(base + (size_t)(2 * k + 2) * HW, r0off);  // issue next-plane loads
        float4 v1 = poolPlane(A, t, h0ok);                      // plane 2k+1 finishes window k
        storeK(k, fmax4(acc, v1));
        A = loadPlane(base + (size_t)(2 * k + 3) * HW, r0off);  // issue next-plane loads
        float4 v2 = poolPlane(B, t, h0ok);                      // plane 2k+2 starts window k+1
        acc = fmax4(v1, v2);
    }
    const int kl = k0 + KPB - 1;                                // last window: planes ..2kl+1
    storeK(kl, fmax4(acc, poolPlane(A, t, h0ok)));
}

extern "C" void kernel_launch(void* const* d_in, const int* in_sizes, int n_in,
                              void* d_out, int out_size, void* d_ws, size_t ws_size,
                              hipStream_t stream) {
    const float* x = (const float*)d_in[0];
    float* out = (float*)d_out;
    dim3 grid(H_OUT / 16, D_OUT / KPB, NC);   // 4 x 8 x 64 = 2048 blocks
    dim3 block(256);
    maxpool3d_k3s2p1_v4<<<grid, block, 0, stream>>>(x, out);
}